// Round 3
// baseline (2625.692 us; speedup 1.0000x reference)
//
#include <hip/hip_runtime.h>
#include <cstdint>
#include <cstddef>

#define NPTS 8192
#define MCTR 2048
#define BATCH 4
#define KNB 32

typedef float v2f __attribute__((ext_vector_type(2)));

// packed fp32 ops — IEEE rn per half, bit-identical to scalar v_add/v_mul
__device__ __forceinline__ v2f pk_add(v2f a, v2f b) {
  v2f d; asm("v_pk_add_f32 %0, %1, %2" : "=v"(d) : "v"(a), "v"(b)); return d;
}
__device__ __forceinline__ v2f pk_mul(v2f a, v2f b) {
  v2f d; asm("v_pk_mul_f32 %0, %1, %2" : "=v"(d) : "v"(a), "v"(b)); return d;
}

// DPP 64-lane max for non-negative floats (identity 0). Result broadcast via SGPR.
__device__ __forceinline__ float wave_max_nonneg(float x) {
  int t;
  t = __builtin_amdgcn_update_dpp(0, __float_as_int(x), 0x111, 0xf, 0xf, false);
  x = fmaxf(x, __int_as_float(t));
  t = __builtin_amdgcn_update_dpp(0, __float_as_int(x), 0x112, 0xf, 0xf, false);
  x = fmaxf(x, __int_as_float(t));
  t = __builtin_amdgcn_update_dpp(0, __float_as_int(x), 0x114, 0xf, 0xf, false);
  x = fmaxf(x, __int_as_float(t));
  t = __builtin_amdgcn_update_dpp(0, __float_as_int(x), 0x118, 0xf, 0xf, false);
  x = fmaxf(x, __int_as_float(t));
  t = __builtin_amdgcn_update_dpp(0, __float_as_int(x), 0x142, 0xa, 0xf, false);
  x = fmaxf(x, __int_as_float(t));
  t = __builtin_amdgcn_update_dpp(0, __float_as_int(x), 0x143, 0xc, 0xf, false);
  x = fmaxf(x, __int_as_float(t));
  return __int_as_float(__builtin_amdgcn_readlane(__float_as_int(x), 63));
}

__device__ __forceinline__ unsigned long long u64max(unsigned long long a,
                                                     unsigned long long b) {
  return a > b ? a : b;
}

// ---------- feature transpose (B,32,N) -> (B,N,32) ----------
__global__ __launch_bounds__(256) void featT_kernel(const float* __restrict__ feats,
                                                    float* __restrict__ featT) {
  const int bn = blockIdx.x;
  const int b = bn >> 8;
  const int n0 = (bn & 255) * 32;
  __shared__ float tile[32][33];
  const int tx = threadIdx.x & 31, ty = threadIdx.x >> 5;
  const float* src = feats + (size_t)b * 32 * NPTS;
#pragma unroll
  for (int s = 0; s < 4; ++s) {
    int f = ty + 8 * s;
    tile[f][tx] = src[(size_t)f * NPTS + n0 + tx];
  }
  __syncthreads();
  float* dst = featT + ((size_t)b * NPTS + n0) * 32;
#pragma unroll
  for (int s = 0; s < 4; ++s) {
    int n = ty + 8 * s;
    dst[n * 32 + tx] = tile[tx][n];
  }
}

// ---------- weight transpose: W[o][c] -> Wt[c][o] (all 3 layers packed) ----------
__global__ __launch_bounds__(256) void prep_kernel(const float* __restrict__ W1,
                                                   const float* __restrict__ W2,
                                                   const float* __restrict__ W3,
                                                   float* __restrict__ Wt) {
  const int t = blockIdx.x * 256 + threadIdx.x;
  if (t < 2240) { int c = t >> 6, o = t & 63;  Wt[t] = W1[o * 35 + c]; }
  if (t < 4096) { int c = t >> 6, o = t & 63;  Wt[2240 + t] = W2[o * 64 + c]; }
  if (t < 8192) { int c = t >> 7, o = t & 127; Wt[6336 + t] = W3[o * 64 + c]; }
}

// ---------- furthest point sampling: one block per batch ----------
// 512 threads, blocked assignment (thread t owns [16t,16t+16)), coords in LDS,
// packed-fp32 distance update, DPP wave max, u64-key cross-wave reduce,
// one barrier per iteration (double-buffered key slots).
__global__ __launch_bounds__(512) void fps_kernel(const float* __restrict__ coords,
                                                  int* __restrict__ cidx,
                                                  float* __restrict__ centers) {
  const int b = blockIdx.x;
  const float* C = coords + (size_t)b * 3 * NPTS;
  const int tid = threadIdx.x;
  __shared__ float lX[NPTS];
  __shared__ float lY[NPTS];
  __shared__ float lZ[NPTS];
  __shared__ __align__(16) unsigned long long skey[2][8];
  for (int i = tid; i < NPTS; i += 512) {
    lX[i] = C[i];
    lY[i] = C[NPTS + i];
    lZ[i] = C[2 * NPTS + i];
  }
  __syncthreads();
  const int base = tid * 16;
  v2f px[8], py[8], pz[8], dd[8];
#pragma unroll
  for (int p = 0; p < 8; ++p) {
    px[p].x = lX[base + 2 * p]; px[p].y = lX[base + 2 * p + 1];
    py[p].x = lY[base + 2 * p]; py[p].y = lY[base + 2 * p + 1];
    pz[p].x = lZ[base + 2 * p]; pz[p].y = lZ[base + 2 * p + 1];
    dd[p].x = __builtin_inff(); dd[p].y = __builtin_inff();
  }
  int far = 0;
  float cx = lX[0], cy = lY[0], cz = lZ[0];
  const int wave = tid >> 6, lane = tid & 63;
  int buf = 0;
  for (int it = 0; it < MCTR; ++it) {
    if (tid == 0) {
      cidx[b * MCTR + it] = far;
      centers[(size_t)b * 3 * MCTR + it] = cx;
      centers[(size_t)b * 3 * MCTR + MCTR + it] = cy;
      centers[(size_t)b * 3 * MCTR + 2 * MCTR + it] = cz;
    }
    v2f ncx; ncx.x = -cx; ncx.y = -cx;
    v2f ncy; ncy.x = -cy; ncy.y = -cy;
    v2f ncz; ncz.x = -cz; ncz.y = -cz;
    float bv = 0.0f;
    float pm[8];
#pragma unroll
    for (int p = 0; p < 8; ++p) {
      // p + (-c) == p - c exactly; (dx*dx + dy*dy) + dz*dz, rn at every step
      v2f dx = pk_add(px[p], ncx);
      v2f dy = pk_add(py[p], ncy);
      v2f dz = pk_add(pz[p], ncz);
      v2f xx = pk_mul(dx, dx);
      v2f yy = pk_mul(dy, dy);
      v2f zz = pk_mul(dz, dz);
      v2f ss = pk_add(xx, yy);
      v2f d2 = pk_add(ss, zz);
      float nx = fminf(dd[p].x, d2.x);
      float ny = fminf(dd[p].y, d2.y);
      dd[p].x = nx; dd[p].y = ny;
      pm[p] = fmaxf(nx, ny);
      bv = fmaxf(bv, pm[p]);
    }
    const float wv = wave_max_nonneg(bv);
    unsigned long long mk = __ballot(bv == wv);
    int src = (int)__builtin_ctzll(mk);  // lowest lane = lowest index (blocked)
    if (lane == src) {
      int bp = 0;
#pragma unroll
      for (int p = 7; p >= 0; --p) bp = (pm[p] == wv) ? p : bp;
      int bj = 2 * bp + ((dd[bp].x == wv) ? 0 : 1);
      // key: (dist bits << 32) | (8191 - idx): u64 max == (max dist, min idx)
      skey[buf][wave] = ((unsigned long long)__float_as_uint(wv) << 32) |
                        (unsigned int)(8191 - (base + bj));
    }
    __syncthreads();
    const ulonglong2* kp = (const ulonglong2*)skey[buf];
    ulonglong2 k0 = kp[0], k1 = kp[1], k2 = kp[2], k3 = kp[3];
    unsigned long long m0 = u64max(k0.x, k0.y);
    unsigned long long m1 = u64max(k1.x, k1.y);
    unsigned long long m2 = u64max(k2.x, k2.y);
    unsigned long long m3 = u64max(k3.x, k3.y);
    unsigned long long km = u64max(u64max(m0, m1), u64max(m2, m3));
    far = 8191 - (int)(km & 0xffffffffull);
    cx = lX[far];
    cy = lY[far];
    cz = lZ[far];
    buf ^= 1;
  }
}

// ---------- ball query: one wave per center, ordered first-32 collection ----------
__global__ __launch_bounds__(256) void ballq_kernel(const float* __restrict__ coords,
                                                    const int* __restrict__ cidx,
                                                    int* __restrict__ nbidx) {
  const int wib = threadIdx.x >> 6;
  const int gw = blockIdx.x * 4 + wib;  // global center id over B*M
  const int lane = threadIdx.x & 63;
  const int b = gw >> 11;
  const float* C = coords + (size_t)b * 3 * NPTS;
  const int ci = cidx[gw];
  const float cx = C[ci], cy = C[NPTS + ci], cz = C[2 * NPTS + ci];
  // python double 0.2*0.2 demoted to f32 == 0x3D23D70A (NOT 0.2f*0.2f!)
  const float R2 = (float)(0.2 * 0.2);
  __shared__ int sbuf[4][32];
  int* buf = sbuf[wib];
  int count = 0;
  for (int base = 0; base < NPTS && count < 32; base += 64) {
    const int i = base + lane;
    float dx = __fsub_rn(cx, C[i]);
    float dy = __fsub_rn(cy, C[NPTS + i]);
    float dz = __fsub_rn(cz, C[2 * NPTS + i]);
    float d2 = __fadd_rn(__fadd_rn(__fmul_rn(dx, dx), __fmul_rn(dy, dy)), __fmul_rn(dz, dz));
    bool q = d2 < R2;
    unsigned long long mk = __ballot(q ? 1 : 0);
    int pos = count + (int)__popcll(mk & ((1ull << lane) - 1ull));
    if (q && pos < 32) buf[pos] = i;
    count += (int)__popcll(mk);
  }
  __syncthreads();
  if (lane < 32) {
    int cnt = count < 32 ? count : 32;
    int first = (count > 0) ? buf[0] : 0;
    int v = (lane < cnt) ? buf[lane] : first;
    nbidx[(size_t)gw * KNB + lane] = v;
  }
}

// ---------- MLP helpers ----------
__device__ __forceinline__ void layer_accum(const float* __restrict__ Wcol,
                                            const float* __restrict__ X, int Cin,
                                            int ldw, float bias, float acc[32]) {
#pragma unroll
  for (int k = 0; k < 32; ++k) acc[k] = bias;
  for (int c = 0; c < Cin; ++c) {
    float w = Wcol[c * ldw];
    const float4* xr = (const float4*)(X + c * 36);
#pragma unroll
    for (int q = 0; q < 8; ++q) {
      float4 xv = xr[q];
      acc[4 * q + 0] = fmaf(w, xv.x, acc[4 * q + 0]);
      acc[4 * q + 1] = fmaf(w, xv.y, acc[4 * q + 1]);
      acc[4 * q + 2] = fmaf(w, xv.z, acc[4 * q + 2]);
      acc[4 * q + 3] = fmaf(w, xv.w, acc[4 * q + 3]);
    }
  }
}

__device__ __forceinline__ void store_relu(float* __restrict__ row, const float acc[32]) {
#pragma unroll
  for (int q = 0; q < 8; ++q) {
    float4 v;
    v.x = fmaxf(acc[4 * q + 0], 0.f);
    v.y = fmaxf(acc[4 * q + 1], 0.f);
    v.z = fmaxf(acc[4 * q + 2], 0.f);
    v.w = fmaxf(acc[4 * q + 3], 0.f);
    *(float4*)(row + 4 * q) = v;
  }
}

// ---------- gather + 3-layer MLP + maxpool: one wave per center ----------
__global__ __launch_bounds__(64) void mlp_kernel(const float* __restrict__ coords,
                                                 const float* __restrict__ featT,
                                                 const float* __restrict__ Wt,
                                                 const float* __restrict__ b1,
                                                 const float* __restrict__ b2,
                                                 const float* __restrict__ b3,
                                                 const int* __restrict__ cidx,
                                                 const int* __restrict__ nbidx,
                                                 float* __restrict__ outT) {
  const int g = blockIdx.x;
  const int b = g >> 11;
  const int lane = threadIdx.x;
  __shared__ __align__(16) float A[64 * 36];
  __shared__ __align__(16) float Bf[64 * 36];
  const float* C = coords + (size_t)b * 3 * NPTS;
  const int ci = cidx[g];
  const float ccx = C[ci], ccy = C[NPTS + ci], ccz = C[2 * NPTS + ci];
  const int* nb = nbidx + (size_t)g * KNB;
  if (lane < 32) {
    const int n = nb[lane];
    A[0 * 36 + lane] = C[n] - ccx;
    A[1 * 36 + lane] = C[NPTS + n] - ccy;
    A[2 * 36 + lane] = C[2 * NPTS + n] - ccz;
    const float4* f = (const float4*)(featT + ((size_t)b * NPTS + n) * 32);
#pragma unroll
    for (int q = 0; q < 4; ++q) {
      float4 v = f[q];
      A[(3 + 4 * q) * 36 + lane] = v.x;
      A[(4 + 4 * q) * 36 + lane] = v.y;
      A[(5 + 4 * q) * 36 + lane] = v.z;
      A[(6 + 4 * q) * 36 + lane] = v.w;
    }
  } else {
    const int k = lane - 32;
    const int n = nb[k];
    const float4* f = (const float4*)(featT + ((size_t)b * NPTS + n) * 32);
#pragma unroll
    for (int q = 4; q < 8; ++q) {
      float4 v = f[q];
      A[(3 + 4 * q) * 36 + k] = v.x;
      A[(4 + 4 * q) * 36 + k] = v.y;
      A[(5 + 4 * q) * 36 + k] = v.z;
      A[(6 + 4 * q) * 36 + k] = v.w;
    }
  }
  __syncthreads();
  float acc[32];
  // layer 1: 35 -> 64, A -> Bf
  layer_accum(Wt + lane, A, 35, 64, b1[lane], acc);
  store_relu(&Bf[lane * 36], acc);
  __syncthreads();
  // layer 2: 64 -> 64, Bf -> A
  layer_accum(Wt + 2240 + lane, Bf, 64, 64, b2[lane], acc);
  __syncthreads();
  store_relu(&A[lane * 36], acc);
  __syncthreads();
  // layer 3: 64 -> 128 (two halves), A -> maxpool -> outT
  float* outp = outT + (size_t)g * 128;
#pragma unroll 1
  for (int h = 0; h < 2; ++h) {
    layer_accum(Wt + 6336 + h * 64 + lane, A, 64, 128, b3[h * 64 + lane], acc);
    float mx = 0.f;  // relu then max == max then clamp at 0
#pragma unroll
    for (int k = 0; k < 32; ++k) mx = fmaxf(mx, acc[k]);
    outp[h * 64 + lane] = mx;
  }
}

// ---------- output transpose (B,M,128) -> (B,128,M) ----------
__global__ __launch_bounds__(256) void outT_kernel(const float* __restrict__ outT,
                                                   float* __restrict__ out) {
  const int bid = blockIdx.x;
  const int b = bid >> 8;
  const int r = bid & 255;
  const int o0 = (r >> 6) * 32;
  const int m0 = (r & 63) * 32;
  __shared__ float tile[32][33];
  const int tx = threadIdx.x & 31, ty = threadIdx.x >> 5;
  const float* src = outT + ((size_t)b * MCTR + m0) * 128;
#pragma unroll
  for (int s = 0; s < 4; ++s) {
    int m = ty + 8 * s;
    tile[m][tx] = src[(size_t)m * 128 + o0 + tx];
  }
  __syncthreads();
  float* dst = out + ((size_t)b * 128 + o0) * MCTR + m0;
#pragma unroll
  for (int s = 0; s < 4; ++s) {
    int o = ty + 8 * s;
    dst[(size_t)o * MCTR + tx] = tile[tx][o];
  }
}

extern "C" void kernel_launch(void* const* d_in, const int* in_sizes, int n_in,
                              void* d_out, int out_size, void* d_ws, size_t ws_size,
                              hipStream_t stream) {
  (void)in_sizes; (void)n_in; (void)out_size; (void)ws_size;
  const float* feats = (const float*)d_in[0];
  const float* coords = (const float*)d_in[1];
  const float* W1 = (const float*)d_in[2];
  const float* b1 = (const float*)d_in[3];
  const float* W2 = (const float*)d_in[4];
  const float* b2 = (const float*)d_in[5];
  const float* W3 = (const float*)d_in[6];
  const float* b3 = (const float*)d_in[7];
  float* out = (float*)d_out;
  float* centers = out + (size_t)BATCH * 128 * MCTR;  // output 1 region

  float* ws_f = (float*)d_ws;
  float* featT = ws_f;                                     // 1,048,576 f
  float* Wt = ws_f + 1048576;                              //    14,528 f
  int* cidx = (int*)(ws_f + 1048576 + 14528);              //     8,192 i
  int* nbidx = (int*)(ws_f + 1048576 + 14528 + 8192);      //   262,144 i
  float* outTbuf = ws_f + 1048576 + 14528 + 8192 + 262144; // 1,048,576 f

  featT_kernel<<<1024, 256, 0, stream>>>(feats, featT);
  prep_kernel<<<32, 256, 0, stream>>>(W1, W2, W3, Wt);
  fps_kernel<<<BATCH, 512, 0, stream>>>(coords, cidx, centers);
  ballq_kernel<<<2048, 256, 0, stream>>>(coords, cidx, nbidx);
  mlp_kernel<<<BATCH * MCTR, 64, 0, stream>>>(coords, featT, Wt, b1, b2, b3, cidx, nbidx, outTbuf);
  outT_kernel<<<1024, 256, 0, stream>>>(outTbuf, out);
}

// Round 4
// 2116.669 us; speedup vs baseline: 1.2405x; 1.2405x over previous
//
#include <hip/hip_runtime.h>
#include <cstdint>
#include <cstddef>

#define NPTS 8192
#define MCTR 2048
#define BATCH 4
#define KNB 32

// DPP 64-lane max for non-negative floats (identity 0). Result broadcast via SGPR.
__device__ __forceinline__ float wave_max_nonneg(float x) {
  int t;
  t = __builtin_amdgcn_update_dpp(0, __float_as_int(x), 0x111, 0xf, 0xf, false);
  x = fmaxf(x, __int_as_float(t));
  t = __builtin_amdgcn_update_dpp(0, __float_as_int(x), 0x112, 0xf, 0xf, false);
  x = fmaxf(x, __int_as_float(t));
  t = __builtin_amdgcn_update_dpp(0, __float_as_int(x), 0x114, 0xf, 0xf, false);
  x = fmaxf(x, __int_as_float(t));
  t = __builtin_amdgcn_update_dpp(0, __float_as_int(x), 0x118, 0xf, 0xf, false);
  x = fmaxf(x, __int_as_float(t));
  t = __builtin_amdgcn_update_dpp(0, __float_as_int(x), 0x142, 0xa, 0xf, false);
  x = fmaxf(x, __int_as_float(t));
  t = __builtin_amdgcn_update_dpp(0, __float_as_int(x), 0x143, 0xc, 0xf, false);
  x = fmaxf(x, __int_as_float(t));
  return __int_as_float(__builtin_amdgcn_readlane(__float_as_int(x), 63));
}

__device__ __forceinline__ unsigned long long u64max(unsigned long long a,
                                                     unsigned long long b) {
  return a > b ? a : b;
}

// ---------- feature transpose (B,32,N) -> (B,N,32) ----------
__global__ __launch_bounds__(256) void featT_kernel(const float* __restrict__ feats,
                                                    float* __restrict__ featT) {
  const int bn = blockIdx.x;
  const int b = bn >> 8;
  const int n0 = (bn & 255) * 32;
  __shared__ float tile[32][33];
  const int tx = threadIdx.x & 31, ty = threadIdx.x >> 5;
  const float* src = feats + (size_t)b * 32 * NPTS;
#pragma unroll
  for (int s = 0; s < 4; ++s) {
    int f = ty + 8 * s;
    tile[f][tx] = src[(size_t)f * NPTS + n0 + tx];
  }
  __syncthreads();
  float* dst = featT + ((size_t)b * NPTS + n0) * 32;
#pragma unroll
  for (int s = 0; s < 4; ++s) {
    int n = ty + 8 * s;
    dst[n * 32 + tx] = tile[tx][n];
  }
}

// ---------- weight transpose: W[o][c] -> Wt[c][o] (all 3 layers packed) ----------
__global__ __launch_bounds__(256) void prep_kernel(const float* __restrict__ W1,
                                                   const float* __restrict__ W2,
                                                   const float* __restrict__ W3,
                                                   float* __restrict__ Wt) {
  const int t = blockIdx.x * 256 + threadIdx.x;
  if (t < 2240) { int c = t >> 6, o = t & 63;  Wt[t] = W1[o * 35 + c]; }
  if (t < 4096) { int c = t >> 6, o = t & 63;  Wt[2240 + t] = W2[o * 64 + c]; }
  if (t < 8192) { int c = t >> 7, o = t & 127; Wt[6336 + t] = W3[o * 64 + c]; }
}

// ---------- furthest point sampling: one block per batch ----------
// 512 threads, blocked assignment (thread t owns [16t,16t+16)), interleaved
// coords in LDS, scalar hot loop (9 inst/pt, no in-loop index tracking),
// max3-tree thread max, DPP wave max, masked winner-only index recovery,
// u64-key cross-wave reduce, one barrier per iteration (double-buffered keys).
__global__ __launch_bounds__(512) void fps_kernel(const float* __restrict__ coords,
                                                  int* __restrict__ cidx,
                                                  float* __restrict__ centers) {
  const int b = blockIdx.x;
  const float* C = coords + (size_t)b * 3 * NPTS;
  const int tid = threadIdx.x;
  __shared__ float lC[NPTS * 3];
  __shared__ __align__(16) unsigned long long skey[2][8];
  for (int i = tid; i < NPTS; i += 512) {
    float x = C[i], y = C[NPTS + i], z = C[2 * NPTS + i];
    lC[3 * i] = x;
    lC[3 * i + 1] = y;
    lC[3 * i + 2] = z;
  }
  __syncthreads();
  const int base = tid * 16;
  float px[16], py[16], pz[16], dd[16];
#pragma unroll
  for (int j = 0; j < 16; ++j) {
    px[j] = lC[3 * (base + j)];
    py[j] = lC[3 * (base + j) + 1];
    pz[j] = lC[3 * (base + j) + 2];
    dd[j] = __builtin_inff();
  }
  int far = 0;
  float cx = lC[0], cy = lC[1], cz = lC[2];
  const int wave = tid >> 6, lane = tid & 63;
  int buf = 0;
  for (int it = 0; it < MCTR; ++it) {
    if (tid == 0) {
      cidx[b * MCTR + it] = far;
      centers[(size_t)b * 3 * MCTR + it] = cx;
      centers[(size_t)b * 3 * MCTR + MCTR + it] = cy;
      centers[(size_t)b * 3 * MCTR + 2 * MCTR + it] = cz;
    }
#pragma unroll
    for (int j = 0; j < 16; ++j) {
      // EXACT order to match numpy: (dx*dx + dy*dy) + dz*dz, no FMA contraction
      float dx = __fsub_rn(px[j], cx);
      float dy = __fsub_rn(py[j], cy);
      float dz = __fsub_rn(pz[j], cz);
      float d = __fadd_rn(__fadd_rn(__fmul_rn(dx, dx), __fmul_rn(dy, dy)), __fmul_rn(dz, dz));
      dd[j] = fminf(dd[j], d);
    }
    // thread max via max3-friendly tree (max is exact; no rounding concerns)
    float a0 = fmaxf(fmaxf(dd[0], dd[1]), dd[2]);
    float a1 = fmaxf(fmaxf(dd[3], dd[4]), dd[5]);
    float a2 = fmaxf(fmaxf(dd[6], dd[7]), dd[8]);
    float a3 = fmaxf(fmaxf(dd[9], dd[10]), dd[11]);
    float a4 = fmaxf(fmaxf(dd[12], dd[13]), dd[14]);
    float b0 = fmaxf(fmaxf(a0, a1), a2);
    float b1 = fmaxf(fmaxf(a3, a4), dd[15]);
    float tv = fmaxf(b0, b1);
    const float wv = wave_max_nonneg(tv);
    unsigned long long mk = __ballot(tv == wv);
    if (lane == (int)__builtin_ctzll(mk)) {  // lowest lane = lowest index (blocked)
      int bj = 0;
#pragma unroll
      for (int j = 15; j >= 0; --j) bj = (dd[j] == wv) ? j : bj;  // first j w/ max
      // key: (dist bits << 32) | (8191 - idx): u64 max == (max dist, min idx)
      skey[buf][wave] = ((unsigned long long)__float_as_uint(wv) << 32) |
                        (unsigned int)(8191 - (base + bj));
    }
    __syncthreads();
    const ulonglong2* kp = (const ulonglong2*)skey[buf];
    ulonglong2 k0 = kp[0], k1 = kp[1], k2 = kp[2], k3 = kp[3];
    unsigned long long km =
        u64max(u64max(u64max(k0.x, k0.y), u64max(k1.x, k1.y)),
               u64max(u64max(k2.x, k2.y), u64max(k3.x, k3.y)));
    far = 8191 - (int)(km & 0xffffffffull);
    cx = lC[3 * far];
    cy = lC[3 * far + 1];
    cz = lC[3 * far + 2];
    buf ^= 1;
  }
}

// ---------- ball query: one wave per center, ordered first-32 collection ----------
__global__ __launch_bounds__(256) void ballq_kernel(const float* __restrict__ coords,
                                                    const int* __restrict__ cidx,
                                                    int* __restrict__ nbidx) {
  const int wib = threadIdx.x >> 6;
  const int gw = blockIdx.x * 4 + wib;  // global center id over B*M
  const int lane = threadIdx.x & 63;
  const int b = gw >> 11;
  const float* C = coords + (size_t)b * 3 * NPTS;
  const int ci = cidx[gw];
  const float cx = C[ci], cy = C[NPTS + ci], cz = C[2 * NPTS + ci];
  // python double 0.2*0.2 demoted to f32 == 0x3D23D70A (NOT 0.2f*0.2f!)
  const float R2 = (float)(0.2 * 0.2);
  __shared__ int sbuf[4][32];
  int* buf = sbuf[wib];
  int count = 0;
  for (int base = 0; base < NPTS && count < 32; base += 64) {
    const int i = base + lane;
    float dx = __fsub_rn(cx, C[i]);
    float dy = __fsub_rn(cy, C[NPTS + i]);
    float dz = __fsub_rn(cz, C[2 * NPTS + i]);
    float d2 = __fadd_rn(__fadd_rn(__fmul_rn(dx, dx), __fmul_rn(dy, dy)), __fmul_rn(dz, dz));
    bool q = d2 < R2;
    unsigned long long mk = __ballot(q ? 1 : 0);
    int pos = count + (int)__popcll(mk & ((1ull << lane) - 1ull));
    if (q && pos < 32) buf[pos] = i;
    count += (int)__popcll(mk);
  }
  __syncthreads();
  if (lane < 32) {
    int cnt = count < 32 ? count : 32;
    int first = (count > 0) ? buf[0] : 0;
    int v = (lane < cnt) ? buf[lane] : first;
    nbidx[(size_t)gw * KNB + lane] = v;
  }
}

// ---------- MLP helpers ----------
__device__ __forceinline__ void layer_accum(const float* __restrict__ Wcol,
                                            const float* __restrict__ X, int Cin,
                                            int ldw, float bias, float acc[32]) {
#pragma unroll
  for (int k = 0; k < 32; ++k) acc[k] = bias;
  for (int c = 0; c < Cin; ++c) {
    float w = Wcol[c * ldw];
    const float4* xr = (const float4*)(X + c * 36);
#pragma unroll
    for (int q = 0; q < 8; ++q) {
      float4 xv = xr[q];
      acc[4 * q + 0] = fmaf(w, xv.x, acc[4 * q + 0]);
      acc[4 * q + 1] = fmaf(w, xv.y, acc[4 * q + 1]);
      acc[4 * q + 2] = fmaf(w, xv.z, acc[4 * q + 2]);
      acc[4 * q + 3] = fmaf(w, xv.w, acc[4 * q + 3]);
    }
  }
}

__device__ __forceinline__ void store_relu(float* __restrict__ row, const float acc[32]) {
#pragma unroll
  for (int q = 0; q < 8; ++q) {
    float4 v;
    v.x = fmaxf(acc[4 * q + 0], 0.f);
    v.y = fmaxf(acc[4 * q + 1], 0.f);
    v.z = fmaxf(acc[4 * q + 2], 0.f);
    v.w = fmaxf(acc[4 * q + 3], 0.f);
    *(float4*)(row + 4 * q) = v;
  }
}

// ---------- gather + 3-layer MLP + maxpool: one wave per center ----------
__global__ __launch_bounds__(64) void mlp_kernel(const float* __restrict__ coords,
                                                 const float* __restrict__ featT,
                                                 const float* __restrict__ Wt,
                                                 const float* __restrict__ b1,
                                                 const float* __restrict__ b2,
                                                 const float* __restrict__ b3,
                                                 const int* __restrict__ cidx,
                                                 const int* __restrict__ nbidx,
                                                 float* __restrict__ outT) {
  const int g = blockIdx.x;
  const int b = g >> 11;
  const int lane = threadIdx.x;
  __shared__ __align__(16) float A[64 * 36];
  __shared__ __align__(16) float Bf[64 * 36];
  const float* C = coords + (size_t)b * 3 * NPTS;
  const int ci = cidx[g];
  const float ccx = C[ci], ccy = C[NPTS + ci], ccz = C[2 * NPTS + ci];
  const int* nb = nbidx + (size_t)g * KNB;
  if (lane < 32) {
    const int n = nb[lane];
    A[0 * 36 + lane] = C[n] - ccx;
    A[1 * 36 + lane] = C[NPTS + n] - ccy;
    A[2 * 36 + lane] = C[2 * NPTS + n] - ccz;
    const float4* f = (const float4*)(featT + ((size_t)b * NPTS + n) * 32);
#pragma unroll
    for (int q = 0; q < 4; ++q) {
      float4 v = f[q];
      A[(3 + 4 * q) * 36 + lane] = v.x;
      A[(4 + 4 * q) * 36 + lane] = v.y;
      A[(5 + 4 * q) * 36 + lane] = v.z;
      A[(6 + 4 * q) * 36 + lane] = v.w;
    }
  } else {
    const int k = lane - 32;
    const int n = nb[k];
    const float4* f = (const float4*)(featT + ((size_t)b * NPTS + n) * 32);
#pragma unroll
    for (int q = 4; q < 8; ++q) {
      float4 v = f[q];
      A[(3 + 4 * q) * 36 + k] = v.x;
      A[(4 + 4 * q) * 36 + k] = v.y;
      A[(5 + 4 * q) * 36 + k] = v.z;
      A[(6 + 4 * q) * 36 + k] = v.w;
    }
  }
  __syncthreads();
  float acc[32];
  // layer 1: 35 -> 64, A -> Bf
  layer_accum(Wt + lane, A, 35, 64, b1[lane], acc);
  store_relu(&Bf[lane * 36], acc);
  __syncthreads();
  // layer 2: 64 -> 64, Bf -> A
  layer_accum(Wt + 2240 + lane, Bf, 64, 64, b2[lane], acc);
  __syncthreads();
  store_relu(&A[lane * 36], acc);
  __syncthreads();
  // layer 3: 64 -> 128 (two halves), A -> maxpool -> outT
  float* outp = outT + (size_t)g * 128;
#pragma unroll 1
  for (int h = 0; h < 2; ++h) {
    layer_accum(Wt + 6336 + h * 64 + lane, A, 64, 128, b3[h * 64 + lane], acc);
    float mx = 0.f;  // relu then max == max then clamp at 0
#pragma unroll
    for (int k = 0; k < 32; ++k) mx = fmaxf(mx, acc[k]);
    outp[h * 64 + lane] = mx;
  }
}

// ---------- output transpose (B,M,128) -> (B,128,M) ----------
__global__ __launch_bounds__(256) void outT_kernel(const float* __restrict__ outT,
                                                   float* __restrict__ out) {
  const int bid = blockIdx.x;
  const int b = bid >> 8;
  const int r = bid & 255;
  const int o0 = (r >> 6) * 32;
  const int m0 = (r & 63) * 32;
  __shared__ float tile[32][33];
  const int tx = threadIdx.x & 31, ty = threadIdx.x >> 5;
  const float* src = outT + ((size_t)b * MCTR + m0) * 128;
#pragma unroll
  for (int s = 0; s < 4; ++s) {
    int m = ty + 8 * s;
    tile[m][tx] = src[(size_t)m * 128 + o0 + tx];
  }
  __syncthreads();
  float* dst = out + ((size_t)b * 128 + o0) * MCTR + m0;
#pragma unroll
  for (int s = 0; s < 4; ++s) {
    int o = ty + 8 * s;
    dst[(size_t)o * MCTR + tx] = tile[tx][o];
  }
}

extern "C" void kernel_launch(void* const* d_in, const int* in_sizes, int n_in,
                              void* d_out, int out_size, void* d_ws, size_t ws_size,
                              hipStream_t stream) {
  (void)in_sizes; (void)n_in; (void)out_size; (void)ws_size;
  const float* feats = (const float*)d_in[0];
  const float* coords = (const float*)d_in[1];
  const float* W1 = (const float*)d_in[2];
  const float* b1 = (const float*)d_in[3];
  const float* W2 = (const float*)d_in[4];
  const float* b2 = (const float*)d_in[5];
  const float* W3 = (const float*)d_in[6];
  const float* b3 = (const float*)d_in[7];
  float* out = (float*)d_out;
  float* centers = out + (size_t)BATCH * 128 * MCTR;  // output 1 region

  float* ws_f = (float*)d_ws;
  float* featT = ws_f;                                     // 1,048,576 f
  float* Wt = ws_f + 1048576;                              //    14,528 f
  int* cidx = (int*)(ws_f + 1048576 + 14528);              //     8,192 i
  int* nbidx = (int*)(ws_f + 1048576 + 14528 + 8192);      //   262,144 i
  float* outTbuf = ws_f + 1048576 + 14528 + 8192 + 262144; // 1,048,576 f

  featT_kernel<<<1024, 256, 0, stream>>>(feats, featT);
  prep_kernel<<<32, 256, 0, stream>>>(W1, W2, W3, Wt);
  fps_kernel<<<BATCH, 512, 0, stream>>>(coords, cidx, centers);
  ballq_kernel<<<2048, 256, 0, stream>>>(coords, cidx, nbidx);
  mlp_kernel<<<BATCH * MCTR, 64, 0, stream>>>(coords, featT, Wt, b1, b2, b3, cidx, nbidx, outTbuf);
  outT_kernel<<<1024, 256, 0, stream>>>(outTbuf, out);
}